// Round 7
// baseline (303.713 us; speedup 1.0000x reference)
//
#include <hip/hip_runtime.h>

// Problem constants (setup_inputs is fixed: B=2, S=2048)
#define DIMSZ 2048
#define NHEAD 16
#define NKV 4
#define HD 128
#define QKVD 3072        // fused q|k|v row stride
#define SEQ 2048
#define NTOK 4096        // B*S

typedef __attribute__((ext_vector_type(8))) short short8;
typedef __attribute__((ext_vector_type(4))) float f32x4;
typedef __attribute__((ext_vector_type(16))) float f32x16;
typedef unsigned short u16;

__device__ __forceinline__ u16 f2bf(float x) {
  union { float f; unsigned u; } v; v.f = x;
  unsigned r = v.u + 0x7fffu + ((v.u >> 16) & 1u);  // RNE
  return (u16)(r >> 16);
}
// pack two f32 -> bf16x2 (round-half-up; values are nonneg probs)
__device__ __forceinline__ unsigned pack_bf2(float a, float b) {
  unsigned ua = __float_as_uint(a) + 0x8000u;
  unsigned ub = __float_as_uint(b) + 0x8000u;
  return __builtin_amdgcn_perm(ub, ua, 0x07060302);  // [ub.hi16 : ua.hi16]
}

// async global->LDS, 16B/lane. LDS dest = wave-uniform base + lane*16.
__device__ __forceinline__ void gl_lds16(const void* g, void* l) {
  __builtin_amdgcn_global_load_lds(
      (const __attribute__((address_space(1))) void*)g,
      (__attribute__((address_space(3))) void*)l, 16, 0, 0);
}

template <int N> __device__ __forceinline__ void vmw() {
  asm volatile("s_waitcnt vmcnt(%0)" :: "n"(N) : "memory");
}
__device__ __forceinline__ void barsb() {
  __builtin_amdgcn_s_barrier();
  __builtin_amdgcn_sched_barrier(0);
}

// ---------------------------------------------------------------------------
// Fused f32 -> bf16 cast for all inputs (x | Wq | Wk | Wv | Wo), 4 elem/thread
// ---------------------------------------------------------------------------
__global__ __launch_bounds__(256)
void castAll(const float* __restrict__ x,  const float* __restrict__ Wq,
             const float* __restrict__ Wk, const float* __restrict__ Wv,
             const float* __restrict__ Wo, u16* __restrict__ xb,
             u16* __restrict__ Wqkvb, u16* __restrict__ Wob) {
  int i = blockIdx.x * 256 + threadIdx.x;   // uint4 index, total 4718592
  int f = i * 4;
  const float* src; u16* dst; int off;
  if (f < 8388608)       { src = x;  dst = xb;    off = f; }
  else if (f < 12582912) { src = Wq; dst = Wqkvb; off = f - 8388608; }
  else if (f < 13631488) { src = Wk; dst = Wqkvb + 4194304; off = f - 12582912; }
  else if (f < 14680064) { src = Wv; dst = Wqkvb + 5242880; off = f - 13631488; }
  else                   { src = Wo; dst = Wob;   off = f - 14680064; }
  float4 v = *(const float4*)(src + off);
  ushort4 o;
  o.x = f2bf(v.x); o.y = f2bf(v.y); o.z = f2bf(v.z); o.w = f2bf(v.w);
  *(ushort4*)(dst + off) = o;
}

// ---------------------------------------------------------------------------
// C[M,N] = A[M,K] @ W[N,K]^T  (bf16 in, fp32 accum).
// BM=256, BN=NCT*64 tile, BK=64, 8 waves (2M x 4N). Grid = (M/256)*(N/BN),
// sized to EXACTLY 256 blocks for both problem shapes (full CU fill).
// Schedule: 4 phases per 2 K-tiles; ds_reads injected inside the previous
// phase's MFMA window; one barrier per phase; counted vmcnt gates.
// (unchanged from round 4 — verified passing)
// ---------------------------------------------------------------------------
template <int NCT, bool F32OUT>
__global__ __launch_bounds__(512, 2)
void gemmX(const u16* __restrict__ A, const u16* __restrict__ W,
           void* __restrict__ Cv, int M, int N, int K) {
  __shared__ __align__(16) u16 As[2][256][64];        // 64 KB
  __shared__ __align__(16) u16 Bs[2][NCT * 64][64];   // 48/32 KB
  const int tid = threadIdx.x;
  const int l = tid & 63;
  const int w = tid >> 6;
  const int r = l & 15, q = l >> 4;
  const int wm = (w >> 2) * 128;          // wave's 128-row M group
  const int wn = (w & 3) * (NCT * 16);    // wave's N group

  // T1: bijective XCD swizzle (grid == 256, divisible by 8)
  const int nx  = N / (NCT * 64);
  const int cpx = gridDim.x >> 3;
  const int lid = (blockIdx.x & 7) * cpx + (blockIdx.x >> 3);
  const int m0 = (lid / nx) << 8;
  const int n0 = (lid % nx) * (NCT * 64);

  // staging lane constants; source chunk inverse-swizzled so linear LDS dest
  // + swizzled read match (rule 21). Unit = 64 rows, wave stages 8 rows.
  const int scol = ((l & 7) ^ (l >> 3)) << 3;
  const u16* Asrc = A + (long)(m0 + w * 8 + (l >> 3)) * K + scol;
  const u16* Bsrc = W + (long)(n0 + w * 8 + (l >> 3)) * K + scol;

  auto stA = [&](int d, int u, int kt) {
    gl_lds16(Asrc + (long)(u * 64) * K + kt * 64, &As[d][u * 64 + w * 8][0]);
  };
  auto stB = [&](int d, int u, int kt) {
    gl_lds16(Bsrc + (long)(u * 64) * K + kt * 64, &Bs[d][u * 64 + w * 8][0]);
  };
  // T2 swizzled fragment reads: slot = (ks*4+q) ^ (row&7); row&7 == r&7.
  auto lda = [&](int d, int rt, int ks) -> short8 {
    return *(const short8*)&As[d][wm + rt * 16 + r][(((ks << 2) | q) ^ (r & 7)) << 3];
  };
  auto ldb = [&](int d, int ct, int ks) -> short8 {
    return *(const short8*)&Bs[d][wn + ct * 16 + r][(((ks << 2) | q) ^ (r & 7)) << 3];
  };

  f32x4 acc[8][NCT] = {};
  short8 a[4][2];         // current A frags (rt0-3 / rt4-7, time-shared)
  short8 bE[NCT][2];      // b frags for even K-tile (buf0)
  short8 bO[NCT][2];      // b frags for odd K-tile (buf1)

#define QUAD(i_, AB, BR)                                                      \
  _Pragma("unroll") for (int ks_ = 0; ks_ < 2; ++ks_)                         \
  _Pragma("unroll") for (int c_ = 0; c_ < NCT; ++c_)                          \
    acc[(AB) + (i_)][c_] = __builtin_amdgcn_mfma_f32_16x16x32_bf16(           \
        a[i_][ks_], BR[c_][ks_], acc[(AB) + (i_)][c_], 0, 0, 0);

  // ---- prologue: buf0 <- kt0 (all 4+NCT units); buf1 <- kt1 {B*, A0, A2}.
#pragma unroll
  for (int u = 0; u < NCT; ++u) stB(0, u, 0);
  stA(0, 0, 0); stA(0, 1, 0); stA(0, 2, 0); stA(0, 3, 0);
#pragma unroll
  for (int u = 0; u < NCT; ++u) stB(1, u, 1);
  stA(1, 0, 1); stA(1, 2, 1);
  vmw<NCT + 2>();                 // retire buf0 kt0 completely
  barsb();
  // pre-read F1 operands (buf0 a0-3 + bE); compiler waits before first MFMA.
#pragma unroll
  for (int i = 0; i < 4; ++i) { a[i][0] = lda(0, i, 0); a[i][1] = lda(0, i, 1); }
#pragma unroll
  for (int c = 0; c < NCT; ++c) { bE[c][0] = ldb(0, c, 0); bE[c][1] = ldb(0, c, 1); }

  const int niter = K >> 7;       // 2 K-tiles (BK=64) per iteration
  for (int it = 0; it < niter; ++it) {
    const int kt1 = 2 * it + 1, kt2 = 2 * it + 2, kt3 = 2 * it + 3;
    const bool more = (it + 1 < niter);

    // ---- F1: buf0 rt0-3 x bE; inj a <- buf0 rt4-7
    stA(1, 1, kt1); stA(1, 3, kt1);
    __builtin_amdgcn_s_setprio(1);
#pragma unroll
    for (int i_ = 0; i_ < 4; ++i_) {
      QUAD(i_, 0, bE);
      a[i_][0] = lda(0, 4 + i_, 0); a[i_][1] = lda(0, 4 + i_, 1);
    }
    __builtin_amdgcn_s_setprio(0);
    vmw<2>();                                   // b1{B*,A0,A2} landed
    barsb();

    // ---- F2: buf0 rt4-7 x bE; inj a <- buf1 rt0-3, bO <- buf1
    if (more) {
#pragma unroll
      for (int u = 0; u < NCT; ++u) stB(0, u, kt2);
      stA(0, 0, kt2); stA(0, 2, kt2);
    }
    __builtin_amdgcn_s_setprio(1);
#pragma unroll
    for (int i_ = 0; i_ < 4; ++i_) {
      QUAD(i_, 4, bE);
      a[i_][0] = lda(1, i_, 0); a[i_][1] = lda(1, i_, 1);
      if (i_ == 0) {
#pragma unroll
        for (int c = 0; c < NCT; ++c) { bO[c][0] = ldb(1, c, 0); bO[c][1] = ldb(1, c, 1); }
      }
    }
    __builtin_amdgcn_s_setprio(0);
    if (more) vmw<NCT + 2>(); else vmw<0>();    // b1{A1,A3} landed
    barsb();

    // ---- F3: buf1 rt0-3 x bO; inj a <- buf1 rt4-7
    if (more) { stA(0, 1, kt2); stA(0, 3, kt2); }
    __builtin_amdgcn_s_setprio(1);
#pragma unroll
    for (int i_ = 0; i_ < 4; ++i_) {
      QUAD(i_, 0, bO);
      a[i_][0] = lda(1, 4 + i_, 0); a[i_][1] = lda(1, 4 + i_, 1);
    }
    __builtin_amdgcn_s_setprio(0);
    if (more) vmw<2>();                         // b0'{B*,A0,A2} landed
    barsb();

    // ---- F4: buf1 rt4-7 x bO; inj a <- buf0' rt0-3, bE <- buf0' (if more)
    if (more) {
#pragma unroll
      for (int u = 0; u < NCT; ++u) stB(1, u, kt3);
      stA(1, 0, kt3); stA(1, 2, kt3);
    }
    __builtin_amdgcn_s_setprio(1);
#pragma unroll
    for (int i_ = 0; i_ < 4; ++i_) {
      QUAD(i_, 4, bO);
      if (more) {
        a[i_][0] = lda(0, i_, 0); a[i_][1] = lda(0, i_, 1);
        if (i_ == 0) {
#pragma unroll
          for (int c = 0; c < NCT; ++c) { bE[c][0] = ldb(0, c, 0); bE[c][1] = ldb(0, c, 1); }
        }
      }
    }
    __builtin_amdgcn_s_setprio(0);
    if (more) vmw<NCT + 2>();                   // b0'{A1,A3} landed
    barsb();
  }
#undef QUAD

  // epilogue: C[row][col], row = m0+wm+i*16+q*4+t, col = n0+wn+j*16+r
#pragma unroll
  for (int i = 0; i < 8; ++i)
#pragma unroll
    for (int j = 0; j < NCT; ++j) {
      int row = m0 + wm + i * 16 + q * 4;
      int col = n0 + wn + j * 16 + r;
#pragma unroll
      for (int t = 0; t < 4; ++t) {
        if (F32OUT)
          ((float*)Cv)[(long)(row + t) * N + col] = acc[i][j][t];
        else
          ((u16*)Cv)[(long)(row + t) * N + col] = f2bf(acc[i][j][t]);
      }
    }
}

// ---------------------------------------------------------------------------
// Fused prep: blocks [0, 20480): RMSNorm+NTK-RoPE for Q (gain+scale) and K.
//             blocks [20480, 20736): V transpose 64-key slab.
// ---------------------------------------------------------------------------
__global__ __launch_bounds__(256)
void prep(u16* __restrict__ qkv, const float* __restrict__ gain, float qsc,
          u16* __restrict__ vt) {
  if (blockIdx.x < 20480) {
    int gid  = blockIdx.x * 4 + (threadIdx.x >> 6);
    int lane = threadIdx.x & 63;
    int token = gid / 20;
    int idx   = gid % 20;
    int s     = token & (SEQ - 1);
    bool isq  = idx < 16;
    int off   = isq ? idx * HD : 2048 + (idx - 16) * HD;
    float psc = isq ? qsc * gain[idx & 15] : 1.0f;
    u16* p = qkv + (long)token * QKVD + off;
    union { unsigned u; float f; } c1, c2;
    c1.u = ((unsigned)p[lane]) << 16;
    c2.u = ((unsigned)p[lane + 64]) << 16;
    float x1 = c1.f, x2 = c2.f;
    float ss = x1 * x1 + x2 * x2;
#pragma unroll
    for (int d = 1; d < 64; d <<= 1) ss += __shfl_xor(ss, d);
    float rn = rsqrtf(ss * (1.0f / 128.0f) + 1.1920929e-07f) * psc;
    float lb = log2f(10000.0f) + 128.0f / 126.0f;          // log2(NTK base)
    float inv_freq = exp2f(-(float)lane * (lb * (1.0f / 64.0f)));
    float ang = (float)s * inv_freq;
    float sn, cs;
    sincosf(ang, &sn, &cs);
    p[lane]      = f2bf((x1 * cs + x2 * sn) * rn);
    p[lane + 64] = f2bf((-x1 * sn + x2 * cs) * rn);
  } else {
    __shared__ u16 T[128 * 72];
    int bid = blockIdx.x - 20480;           // 0..255 = (SEQ/64=32) x NKV x B
    const int k0 = (bid & 31) * 64, hkv = (bid >> 5) & 3, b = bid >> 7;
    const u16* vb = qkv + 2560;
    const int t = threadIdx.x;
    const int key = t & 63, dh0 = (t >> 6) * 32;
#pragma unroll
    for (int c = 0; c < 4; c++) {
      uint4 vv = *(const uint4*)&vb[(long)(b * SEQ + k0 + key) * QKVD + hkv * HD + dh0 + c * 8];
      u16 tmp[8];
      *(uint4*)tmp = vv;
#pragma unroll
      for (int e = 0; e < 8; e++) T[(dh0 + c * 8 + e) * 72 + key] = tmp[e];
    }
    __syncthreads();
    const int dh = t >> 1, half = t & 1;
#pragma unroll
    for (int c = 0; c < 4; c++) {
      uint4 ov = *(const uint4*)&T[dh * 72 + half * 32 + c * 8];
      *(uint4*)&vt[((long)(b * NKV + hkv) * HD + dh) * SEQ + k0 + half * 32 + c * 8] = ov;
    }
  }
}

// ---------------------------------------------------------------------------
// Flash attention, causal, GQA — round 7: 32x32x16 MFMA + in-register P
// (m214-v22 structure). 4 waves x 32 qrows = 128-row Q tile, KV tile = 64.
// Verified sync structure (stage -> __syncthreads -> compute). No Ps LDS.
//  - QK^T: D[key][qrow], col=lane&31 -> lane owns ONE qrow; 16 regs/kt hold
//    keys crow(g,lh) = (g&3)+8*(g>>2)+4*lh (m74/m101-verified layout).
//  - P -> PV A-frag in-register: 8 pack_bf2 + 4 v_permlane32_swap_b32 per kt
//    rebuild keys into (lh*8..lh*8+7) order (element-wise verified vs m214).
//  - Ks [64][128] 4-bit XOR chunk swizzle; Vt [128][64] 3-bit (both-sides).
//  - no online softmax (RMSNormed q,k bound |score*log2e| <= ~16.4).
//  - grid 512: pairs (bid, bid+256) have qt1+qt2 = 15 -> each CU's 2
//    co-resident blocks total a uniform 34 kv-iters (exact balance).
// ---------------------------------------------------------------------------
__global__ __launch_bounds__(256, 2)
void fattn(const u16* __restrict__ qb, const u16* __restrict__ kb,
           const u16* __restrict__ vtg, u16* __restrict__ yb) {
  __shared__ u16 Ks[64 * 128];    // [key][dh], 16B chunks, 4-bit XOR (16 KB)
  __shared__ u16 Vt[128 * 64];    // [dh][key], 16B chunks, 3-bit XOR (16 KB)
  const int tid = threadIdx.x;
  const int l   = tid & 63;
  const int w   = tid >> 6;        // 0..3
  const int lh  = l >> 5;          // lane half
  const int l31 = l & 31;
  const int bq  = blockIdx.x >> 5;
  const int qt  = (blockIdx.x & 256) ? (bq - 8) : (15 - bq);  // pair-balanced
  const int hb  = blockIdx.x & 31;
  const int h   = hb >> 1;
  const int b   = hb & 1;
  const int q0  = qt * 128;
  const int hkv = h >> 2;
  const int qrow = q0 + w * 32 + l31;   // this lane's q row (global)

  // staging lane constants (linear LDS dest + inverse-swizzled global source)
  int koff[4], voff[4];
  u16 *kdst[4], *vdst[4];
#pragma unroll
  for (int c = 0; c < 4; c++) {
    int gr = w * 16 + c * 4 + (l >> 4);            // K row in tile (0..63)
    int s  = l & 15;
    int kj = s ^ (gr & 15);                        // logical chunk to fetch
    koff[c] = gr * QKVD + hkv * HD + kj * 8;
    kdst[c] = Ks + (w * 16 + c * 4) * 128;
    int dh = w * 32 + c * 8 + (l >> 3);            // Vt row in tile (0..127)
    int vs = l & 7;
    int vj = vs ^ (dh & 7);
    voff[c] = dh * SEQ + vj * 8;
    vdst[c] = Vt + (w * 32 + c * 8) * 64;
  }
  const u16* vbase = vtg + (long)(b * NKV + hkv) * HD * SEQ;

  // Q fragments: lane holds Q[qrow][ks*16 + lh*8 .. +7] for ks = 0..7
  short8 qf[8];
  {
    const u16* qp = qb + (long)(b * SEQ + qrow) * QKVD + h * HD + lh * 8;
#pragma unroll
    for (int ks = 0; ks < 8; ks++)
      qf[ks] = *(const short8*)(qp + ks * 16);
  }

  f32x16 oacc[4] = {};
  float l_i = 0.f;

  // swizzled fragment reads
  auto kfr = [&](int kt, int ks) -> short8 {   // K[key][dh-slice]
    int row = kt * 32 + l31;
    int p = (ks * 2 + lh) ^ (row & 15);
    return *(const short8*)&Ks[row * 128 + p * 8];
  };
  auto vfr = [&](int dt, int kq) -> short8 {   // V^T[dh][key-slice]
    int row = dt * 32 + l31;
    int p = (kq * 2 + lh) ^ (row & 7);
    return *(const short8*)&Vt[row * 64 + p * 8];
  };

  const int kend = q0 + 64;
  for (int k0 = 0; k0 <= kend; k0 += 64) {
    __syncthreads();  // prior iteration's LDS reads done
    const u16* kb_t = kb + (long)(b * SEQ + k0) * QKVD;
    const u16* vb_t = vbase + k0;
#pragma unroll
    for (int c = 0; c < 4; c++) {
      gl_lds16(kb_t + koff[c], kdst[c]);
      gl_lds16(vb_t + voff[c], vdst[c]);
    }
    __syncthreads();  // drains vmcnt -> tiles valid

    const bool diag = (k0 >= q0);

#pragma unroll
    for (int kt = 0; kt < 2; ++kt) {
      // S^T tile: D[key = k0+kt*32+crow(g,lh)][qrow], one qrow per lane
      f32x16 st;
#pragma unroll
      for (int g = 0; g < 16; ++g) st[g] = 0.f;
#pragma unroll
      for (int ks = 0; ks < 8; ++ks)
        st = __builtin_amdgcn_mfma_f32_32x32x16_bf16(kfr(kt, ks), qf[ks], st, 0, 0, 0);

      if (diag) {
#pragma unroll
        for (int g = 0; g < 16; ++g) {
          int key = k0 + kt * 32 + (g & 3) + 8 * (g >> 2) + 4 * lh;
          if (key > qrow) st[g] = -3e38f;
        }
      }

      // p = exp2(s) (bounded, no max-shift), per-lane row-sum
#pragma unroll
      for (int g = 0; g < 16; ++g) {
        float e = exp2f(st[g]);
        st[g] = e;
        l_i += e;
      }

      // in-register P -> bf16 A-frags: 8 packs + 4 permlane32 swaps
      unsigned c8[8];
#pragma unroll
      for (int m = 0; m < 8; ++m) c8[m] = pack_bf2(st[2 * m], st[2 * m + 1]);
      asm("v_permlane32_swap_b32 %0, %1" : "+v"(c8[0]), "+v"(c8[2]));
      asm("v_permlane32_swap_b32 %0, %1" : "+v"(c8[1]), "+v"(c8[3]));
      asm("v_permlane32_swap_b32 %0, %1" : "+v"(c8[4]), "+v"(c8[6]));
      asm("v_permlane32_swap_b32 %0, %1" : "+v"(c8[5]), "+v"(c8[7]));
      union { unsigned u[4]; short8 s; } pa0, pa1;
      pa0.u[0] = c8[0]; pa0.u[1] = c8[1]; pa0.u[2] = c8[2]; pa0.u[3] = c8[3];
      pa1.u[0] = c8[4]; pa1.u[1] = c8[5]; pa1.u[2] = c8[6]; pa1.u[3] = c8[7];

      // O += P @ V   (D[qrow][dh], A = P rows, B = V^T rows)
#pragma unroll
      for (int dt = 0; dt < 4; ++dt) {
        oacc[dt] = __builtin_amdgcn_mfma_f32_32x32x16_bf16(pa0.s, vfr(dt, kt * 2 + 0), oacc[dt], 0, 0, 0);
        oacc[dt] = __builtin_amdgcn_mfma_f32_32x32x16_bf16(pa1.s, vfr(dt, kt * 2 + 1), oacc[dt], 0, 0, 0);
      }
    }
  }

  // epilogue: lane pair (l, l^32) holds complementary keys of the same qrow
  l_i += __shfl_xor(l_i, 32);
  float linv = 1.0f / l_i;
#pragma unroll
  for (int g = 0; g < 16; ++g) {
    int qrl = (g & 3) + 8 * (g >> 2) + 4 * lh;        // qrow index within wave
    float lg = __shfl(linv, qrl);                     // lane qrl holds that row's sum
    long rowoff = (long)(b * SEQ + q0 + w * 32 + qrl) * DIMSZ + h * HD + l31;
#pragma unroll
    for (int dt = 0; dt < 4; ++dt)
      yb[rowoff + dt * 32] = f2bf(oacc[dt][g] * lg);
  }
}

// ---------------------------------------------------------------------------
extern "C" void kernel_launch(void* const* d_in, const int* in_sizes, int n_in,
                              void* d_out, int out_size, void* d_ws, size_t ws_size,
                              hipStream_t stream) {
  const float* x  = (const float*)d_in[0];
  const float* Wq = (const float*)d_in[1];
  const float* Wk = (const float*)d_in[2];
  const float* Wv = (const float*)d_in[3];
  const float* Wo = (const float*)d_in[4];
  const float* qg = (const float*)d_in[5];
  float* out = (float*)d_out;

  const long MB = 1024 * 1024;
  char* ws = (char*)d_ws;
  u16* xb    = (u16*)(ws + 0 * MB);    // 16 MB (dead after QKV GEMM)
  u16* ybuf  = (u16*)(ws + 0 * MB);    // 16 MB (aliases xb; written by fattn)
  u16* Wqkvb = (u16*)(ws + 16 * MB);   // 12 MB
  u16* Wob   = (u16*)(ws + 28 * MB);   // 8 MB
  u16* qkv   = (u16*)(ws + 36 * MB);   // 24 MB
  u16* vtg   = (u16*)(ws + 60 * MB);   // 4 MB (V transposed)

  castAll<<<18432, 256, 0, stream>>>(x, Wq, Wk, Wv, Wo, xb, Wqkvb, Wob);

  // QKV GEMM: M=4096, N=3072; 256x192 tiles -> 16x16 = 256 blocks (full fill)
  gemmX<3, false><<<256, 512, 0, stream>>>(xb, Wqkvb, qkv, NTOK, QKVD, DIMSZ);

  const float qsc = 0.08838834764831845f * 1.44269504088896f;  // scale*log2e
  prep<<<20736, 256, 0, stream>>>(qkv, qg, qsc, vtg);

  // 16 q-tiles (128 rows) x 32 (h,b) = 512 blocks of 256 threads,
  // ordered so (bid, bid+256) pair to a uniform 34 kv-iters per CU.
  fattn<<<512, 256, 0, stream>>>(qkv, qkv + 2048, vtg, ybuf);

  // Output GEMM: M=4096, N=2048; 256x128 tiles -> 16x16 = 256 blocks
  gemmX<2, true><<<256, 512, 0, stream>>>(ybuf, Wob, out, NTOK, DIMSZ, DIMSZ);
}

// Round 8
// 292.643 us; speedup vs baseline: 1.0378x; 1.0378x over previous
//
#include <hip/hip_runtime.h>

// Problem constants (setup_inputs is fixed: B=2, S=2048)
#define DIMSZ 2048
#define NHEAD 16
#define NKV 4
#define HD 128
#define QKVD 3072        // fused q|k|v row stride
#define SEQ 2048
#define NTOK 4096        // B*S

typedef __attribute__((ext_vector_type(8))) short short8;
typedef __attribute__((ext_vector_type(4))) float f32x4;
typedef __attribute__((ext_vector_type(16))) float f32x16;
typedef unsigned short u16;

__device__ __forceinline__ u16 f2bf(float x) {
  union { float f; unsigned u; } v; v.f = x;
  unsigned r = v.u + 0x7fffu + ((v.u >> 16) & 1u);  // RNE
  return (u16)(r >> 16);
}
// pack two f32 -> bf16x2 (round-half-up; values are nonneg probs)
__device__ __forceinline__ unsigned pack_bf2(float a, float b) {
  unsigned ua = __float_as_uint(a) + 0x8000u;
  unsigned ub = __float_as_uint(b) + 0x8000u;
  return __builtin_amdgcn_perm(ub, ua, 0x07060302);  // [ub.hi16 : ua.hi16]
}

// async global->LDS, 16B/lane. LDS dest = wave-uniform base + lane*16.
__device__ __forceinline__ void gl_lds16(const void* g, void* l) {
  __builtin_amdgcn_global_load_lds(
      (const __attribute__((address_space(1))) void*)g,
      (__attribute__((address_space(3))) void*)l, 16, 0, 0);
}

template <int N> __device__ __forceinline__ void vmw() {
  asm volatile("s_waitcnt vmcnt(%0)" :: "n"(N) : "memory");
}
__device__ __forceinline__ void barsb() {
  __builtin_amdgcn_s_barrier();
  __builtin_amdgcn_sched_barrier(0);
}

// ---------------------------------------------------------------------------
// Fused f32 -> bf16 cast for all inputs (x | Wq | Wk | Wv | Wo), 4 elem/thread
// ---------------------------------------------------------------------------
__global__ __launch_bounds__(256)
void castAll(const float* __restrict__ x,  const float* __restrict__ Wq,
             const float* __restrict__ Wk, const float* __restrict__ Wv,
             const float* __restrict__ Wo, u16* __restrict__ xb,
             u16* __restrict__ Wqkvb, u16* __restrict__ Wob) {
  int i = blockIdx.x * 256 + threadIdx.x;   // uint4 index, total 4718592
  int f = i * 4;
  const float* src; u16* dst; int off;
  if (f < 8388608)       { src = x;  dst = xb;    off = f; }
  else if (f < 12582912) { src = Wq; dst = Wqkvb; off = f - 8388608; }
  else if (f < 13631488) { src = Wk; dst = Wqkvb + 4194304; off = f - 12582912; }
  else if (f < 14680064) { src = Wv; dst = Wqkvb + 5242880; off = f - 13631488; }
  else                   { src = Wo; dst = Wob;   off = f - 14680064; }
  float4 v = *(const float4*)(src + off);
  ushort4 o;
  o.x = f2bf(v.x); o.y = f2bf(v.y); o.z = f2bf(v.z); o.w = f2bf(v.w);
  *(ushort4*)(dst + off) = o;
}

// ---------------------------------------------------------------------------
// C[M,N] = A[M,K] @ W[N,K]^T  (bf16 in, fp32 accum).
// BM=256, BN=NCT*64 tile, BK=64, 8 waves (2M x 4N). Grid = (M/256)*(N/BN),
// sized to EXACTLY 256 blocks for both problem shapes (full CU fill).
// Schedule: 4 phases per 2 K-tiles; ds_reads injected inside the previous
// phase's MFMA window; one barrier per phase; counted vmcnt gates.
// (unchanged from round 4 — verified passing)
// ---------------------------------------------------------------------------
template <int NCT, bool F32OUT>
__global__ __launch_bounds__(512, 2)
void gemmX(const u16* __restrict__ A, const u16* __restrict__ W,
           void* __restrict__ Cv, int M, int N, int K) {
  __shared__ __align__(16) u16 As[2][256][64];        // 64 KB
  __shared__ __align__(16) u16 Bs[2][NCT * 64][64];   // 48/32 KB
  const int tid = threadIdx.x;
  const int l = tid & 63;
  const int w = tid >> 6;
  const int r = l & 15, q = l >> 4;
  const int wm = (w >> 2) * 128;          // wave's 128-row M group
  const int wn = (w & 3) * (NCT * 16);    // wave's N group

  // T1: bijective XCD swizzle (grid == 256, divisible by 8)
  const int nx  = N / (NCT * 64);
  const int cpx = gridDim.x >> 3;
  const int lid = (blockIdx.x & 7) * cpx + (blockIdx.x >> 3);
  const int m0 = (lid / nx) << 8;
  const int n0 = (lid % nx) * (NCT * 64);

  // staging lane constants; source chunk inverse-swizzled so linear LDS dest
  // + swizzled read match (rule 21). Unit = 64 rows, wave stages 8 rows.
  const int scol = ((l & 7) ^ (l >> 3)) << 3;
  const u16* Asrc = A + (long)(m0 + w * 8 + (l >> 3)) * K + scol;
  const u16* Bsrc = W + (long)(n0 + w * 8 + (l >> 3)) * K + scol;

  auto stA = [&](int d, int u, int kt) {
    gl_lds16(Asrc + (long)(u * 64) * K + kt * 64, &As[d][u * 64 + w * 8][0]);
  };
  auto stB = [&](int d, int u, int kt) {
    gl_lds16(Bsrc + (long)(u * 64) * K + kt * 64, &Bs[d][u * 64 + w * 8][0]);
  };
  // T2 swizzled fragment reads: slot = (ks*4+q) ^ (row&7); row&7 == r&7.
  auto lda = [&](int d, int rt, int ks) -> short8 {
    return *(const short8*)&As[d][wm + rt * 16 + r][(((ks << 2) | q) ^ (r & 7)) << 3];
  };
  auto ldb = [&](int d, int ct, int ks) -> short8 {
    return *(const short8*)&Bs[d][wn + ct * 16 + r][(((ks << 2) | q) ^ (r & 7)) << 3];
  };

  f32x4 acc[8][NCT] = {};
  short8 a[4][2];         // current A frags (rt0-3 / rt4-7, time-shared)
  short8 bE[NCT][2];      // b frags for even K-tile (buf0)
  short8 bO[NCT][2];      // b frags for odd K-tile (buf1)

#define QUAD(i_, AB, BR)                                                      \
  _Pragma("unroll") for (int ks_ = 0; ks_ < 2; ++ks_)                         \
  _Pragma("unroll") for (int c_ = 0; c_ < NCT; ++c_)                          \
    acc[(AB) + (i_)][c_] = __builtin_amdgcn_mfma_f32_16x16x32_bf16(           \
        a[i_][ks_], BR[c_][ks_], acc[(AB) + (i_)][c_], 0, 0, 0);

  // ---- prologue: buf0 <- kt0 (all 4+NCT units); buf1 <- kt1 {B*, A0, A2}.
#pragma unroll
  for (int u = 0; u < NCT; ++u) stB(0, u, 0);
  stA(0, 0, 0); stA(0, 1, 0); stA(0, 2, 0); stA(0, 3, 0);
#pragma unroll
  for (int u = 0; u < NCT; ++u) stB(1, u, 1);
  stA(1, 0, 1); stA(1, 2, 1);
  vmw<NCT + 2>();                 // retire buf0 kt0 completely
  barsb();
  // pre-read F1 operands (buf0 a0-3 + bE); compiler waits before first MFMA.
#pragma unroll
  for (int i = 0; i < 4; ++i) { a[i][0] = lda(0, i, 0); a[i][1] = lda(0, i, 1); }
#pragma unroll
  for (int c = 0; c < NCT; ++c) { bE[c][0] = ldb(0, c, 0); bE[c][1] = ldb(0, c, 1); }

  const int niter = K >> 7;       // 2 K-tiles (BK=64) per iteration
  for (int it = 0; it < niter; ++it) {
    const int kt1 = 2 * it + 1, kt2 = 2 * it + 2, kt3 = 2 * it + 3;
    const bool more = (it + 1 < niter);

    // ---- F1: buf0 rt0-3 x bE; inj a <- buf0 rt4-7
    stA(1, 1, kt1); stA(1, 3, kt1);
    __builtin_amdgcn_s_setprio(1);
#pragma unroll
    for (int i_ = 0; i_ < 4; ++i_) {
      QUAD(i_, 0, bE);
      a[i_][0] = lda(0, 4 + i_, 0); a[i_][1] = lda(0, 4 + i_, 1);
    }
    __builtin_amdgcn_s_setprio(0);
    vmw<2>();                                   // b1{B*,A0,A2} landed
    barsb();

    // ---- F2: buf0 rt4-7 x bE; inj a <- buf1 rt0-3, bO <- buf1
    if (more) {
#pragma unroll
      for (int u = 0; u < NCT; ++u) stB(0, u, kt2);
      stA(0, 0, kt2); stA(0, 2, kt2);
    }
    __builtin_amdgcn_s_setprio(1);
#pragma unroll
    for (int i_ = 0; i_ < 4; ++i_) {
      QUAD(i_, 4, bE);
      a[i_][0] = lda(1, i_, 0); a[i_][1] = lda(1, i_, 1);
      if (i_ == 0) {
#pragma unroll
        for (int c = 0; c < NCT; ++c) { bO[c][0] = ldb(1, c, 0); bO[c][1] = ldb(1, c, 1); }
      }
    }
    __builtin_amdgcn_s_setprio(0);
    if (more) vmw<NCT + 2>(); else vmw<0>();    // b1{A1,A3} landed
    barsb();

    // ---- F3: buf1 rt0-3 x bO; inj a <- buf1 rt4-7
    if (more) { stA(0, 1, kt2); stA(0, 3, kt2); }
    __builtin_amdgcn_s_setprio(1);
#pragma unroll
    for (int i_ = 0; i_ < 4; ++i_) {
      QUAD(i_, 0, bO);
      a[i_][0] = lda(1, 4 + i_, 0); a[i_][1] = lda(1, 4 + i_, 1);
    }
    __builtin_amdgcn_s_setprio(0);
    if (more) vmw<2>();                         // b0'{B*,A0,A2} landed
    barsb();

    // ---- F4: buf1 rt4-7 x bO; inj a <- buf0' rt0-3, bE <- buf0' (if more)
    if (more) {
#pragma unroll
      for (int u = 0; u < NCT; ++u) stB(1, u, kt3);
      stA(1, 0, kt3); stA(1, 2, kt3);
    }
    __builtin_amdgcn_s_setprio(1);
#pragma unroll
    for (int i_ = 0; i_ < 4; ++i_) {
      QUAD(i_, 4, bO);
      if (more) {
        a[i_][0] = lda(0, i_, 0); a[i_][1] = lda(0, i_, 1);
        if (i_ == 0) {
#pragma unroll
          for (int c = 0; c < NCT; ++c) { bE[c][0] = ldb(0, c, 0); bE[c][1] = ldb(0, c, 1); }
        }
      }
    }
    __builtin_amdgcn_s_setprio(0);
    if (more) vmw<NCT + 2>();                   // b0'{A1,A3} landed
    barsb();
  }
#undef QUAD

  // epilogue: C[row][col], row = m0+wm+i*16+q*4+t, col = n0+wn+j*16+r
#pragma unroll
  for (int i = 0; i < 8; ++i)
#pragma unroll
    for (int j = 0; j < NCT; ++j) {
      int row = m0 + wm + i * 16 + q * 4;
      int col = n0 + wn + j * 16 + r;
#pragma unroll
      for (int t = 0; t < 4; ++t) {
        if (F32OUT)
          ((float*)Cv)[(long)(row + t) * N + col] = acc[i][j][t];
        else
          ((u16*)Cv)[(long)(row + t) * N + col] = f2bf(acc[i][j][t]);
      }
    }
}

// ---------------------------------------------------------------------------
// Fused prep: blocks [0, 20480): RMSNorm+NTK-RoPE for Q (gain+scale) and K.
//             blocks [20480, 20736): V transpose 64-key slab.
// ---------------------------------------------------------------------------
__global__ __launch_bounds__(256)
void prep(u16* __restrict__ qkv, const float* __restrict__ gain, float qsc,
          u16* __restrict__ vt) {
  if (blockIdx.x < 20480) {
    int gid  = blockIdx.x * 4 + (threadIdx.x >> 6);
    int lane = threadIdx.x & 63;
    int token = gid / 20;
    int idx   = gid % 20;
    int s     = token & (SEQ - 1);
    bool isq  = idx < 16;
    int off   = isq ? idx * HD : 2048 + (idx - 16) * HD;
    float psc = isq ? qsc * gain[idx & 15] : 1.0f;
    u16* p = qkv + (long)token * QKVD + off;
    union { unsigned u; float f; } c1, c2;
    c1.u = ((unsigned)p[lane]) << 16;
    c2.u = ((unsigned)p[lane + 64]) << 16;
    float x1 = c1.f, x2 = c2.f;
    float ss = x1 * x1 + x2 * x2;
#pragma unroll
    for (int d = 1; d < 64; d <<= 1) ss += __shfl_xor(ss, d);
    float rn = rsqrtf(ss * (1.0f / 128.0f) + 1.1920929e-07f) * psc;
    float lb = log2f(10000.0f) + 128.0f / 126.0f;          // log2(NTK base)
    float inv_freq = exp2f(-(float)lane * (lb * (1.0f / 64.0f)));
    float ang = (float)s * inv_freq;
    float sn, cs;
    sincosf(ang, &sn, &cs);
    p[lane]      = f2bf((x1 * cs + x2 * sn) * rn);
    p[lane + 64] = f2bf((-x1 * sn + x2 * cs) * rn);
  } else {
    __shared__ u16 T[128 * 72];
    int bid = blockIdx.x - 20480;           // 0..255 = (SEQ/64=32) x NKV x B
    const int k0 = (bid & 31) * 64, hkv = (bid >> 5) & 3, b = bid >> 7;
    const u16* vb = qkv + 2560;
    const int t = threadIdx.x;
    const int key = t & 63, dh0 = (t >> 6) * 32;
#pragma unroll
    for (int c = 0; c < 4; c++) {
      uint4 vv = *(const uint4*)&vb[(long)(b * SEQ + k0 + key) * QKVD + hkv * HD + dh0 + c * 8];
      u16 tmp[8];
      *(uint4*)tmp = vv;
#pragma unroll
      for (int e = 0; e < 8; e++) T[(dh0 + c * 8 + e) * 72 + key] = tmp[e];
    }
    __syncthreads();
    const int dh = t >> 1, half = t & 1;
#pragma unroll
    for (int c = 0; c < 4; c++) {
      uint4 ov = *(const uint4*)&T[dh * 72 + half * 32 + c * 8];
      *(uint4*)&vt[((long)(b * NKV + hkv) * HD + dh) * SEQ + k0 + half * 32 + c * 8] = ov;
    }
  }
}

// ---------------------------------------------------------------------------
// Flash attention, causal, GQA — round 8: r7 structure (32x32x16 MFMA,
// in-register P) + DOUBLE-BUFFERED K/V with prefetch-after-barrier.
// 2-phase pipeline (guide §5.5 T3 minimum, m248-verified pattern):
//   stage(0 -> buf0)
//   loop pairs { __syncthreads; stage(t+1 -> buf1); compute(t, buf0);
//                __syncthreads; stage(t+2 -> buf0); compute(t+1, buf1); }
// One __syncthreads per tile: its implicit vmcnt(0) drains the prefetch
// AFTER a full compute phase has hidden the L2 latency. No manual vmcnt,
// no raw barriers, no counting: writes target the buffer nobody reads this
// phase (WAR impossible); reads gated by drain+barrier (RAW impossible).
// Trip count qt*2+2 is always even -> static buffer unroll (rule 20).
// Everything else identical to the r7 passing kernel.
// ---------------------------------------------------------------------------
__global__ __launch_bounds__(256, 2)
void fattn(const u16* __restrict__ qb, const u16* __restrict__ kb,
           const u16* __restrict__ vtg, u16* __restrict__ yb) {
  __shared__ u16 Ks[2 * 64 * 128];  // [buf][key][dh], 16B chunks, 4-bit XOR (32 KB)
  __shared__ u16 Vt[2 * 128 * 64];  // [buf][dh][key], 16B chunks, 3-bit XOR (32 KB)
  const int tid = threadIdx.x;
  const int l   = tid & 63;
  const int w   = tid >> 6;        // 0..3
  const int lh  = l >> 5;          // lane half
  const int l31 = l & 31;
  const int bq  = blockIdx.x >> 5;
  const int qt  = (blockIdx.x & 256) ? (bq - 8) : (15 - bq);  // pair-balanced
  const int hb  = blockIdx.x & 31;
  const int h   = hb >> 1;
  const int b   = hb & 1;
  const int q0  = qt * 128;
  const int hkv = h >> 2;
  const int qrow = q0 + w * 32 + l31;   // this lane's q row (global)

  // staging lane constants (linear LDS dest + inverse-swizzled global source)
  int koff[4], voff[4];
  u16 *kdst[4], *vdst[4];
#pragma unroll
  for (int c = 0; c < 4; c++) {
    int gr = w * 16 + c * 4 + (l >> 4);            // K row in tile (0..63)
    int s  = l & 15;
    int kj = s ^ (gr & 15);                        // logical chunk to fetch
    koff[c] = gr * QKVD + hkv * HD + kj * 8;
    kdst[c] = Ks + (w * 16 + c * 4) * 128;
    int dh = w * 32 + c * 8 + (l >> 3);            // Vt row in tile (0..127)
    int vs = l & 7;
    int vj = vs ^ (dh & 7);
    voff[c] = dh * SEQ + vj * 8;
    vdst[c] = Vt + (w * 32 + c * 8) * 64;
  }
  const u16* vbase = vtg + (long)(b * NKV + hkv) * HD * SEQ;

  // Q fragments: lane holds Q[qrow][ks*16 + lh*8 .. +7] for ks = 0..7
  short8 qf[8];
  {
    const u16* qp = qb + (long)(b * SEQ + qrow) * QKVD + h * HD + lh * 8;
#pragma unroll
    for (int ks = 0; ks < 8; ks++)
      qf[ks] = *(const short8*)(qp + ks * 16);
  }

  f32x16 oacc[4] = {};
  float l_i = 0.f;

  // stage K/V tile at key-offset k0n into buffer half bo (0 or 8192 elems)
  auto stage = [&](int k0n, int bo) {
    const u16* kb_n = kb + (long)(b * SEQ + k0n) * QKVD;
    const u16* vb_n = vbase + k0n;
#pragma unroll
    for (int c = 0; c < 4; c++) {
      gl_lds16(kb_n + koff[c], kdst[c] + bo);
      gl_lds16(vb_n + voff[c], vdst[c] + bo);
    }
  };

  // compute one 64-key tile from buffer base pointers (ksb, vtb)
  auto compute = [&](int k0c, const u16* ksb, const u16* vtb) {
    const bool diag = (k0c >= q0);
#pragma unroll
    for (int kt = 0; kt < 2; ++kt) {
      // S^T tile: D[key = k0c+kt*32+crow(g,lh)][qrow], one qrow per lane
      f32x16 st;
#pragma unroll
      for (int g = 0; g < 16; ++g) st[g] = 0.f;
#pragma unroll
      for (int ks = 0; ks < 8; ++ks) {
        int row = kt * 32 + l31;
        int p = (ks * 2 + lh) ^ (row & 15);
        short8 kf = *(const short8*)&ksb[row * 128 + p * 8];
        st = __builtin_amdgcn_mfma_f32_32x32x16_bf16(kf, qf[ks], st, 0, 0, 0);
      }

      if (diag) {
#pragma unroll
        for (int g = 0; g < 16; ++g) {
          int key = k0c + kt * 32 + (g & 3) + 8 * (g >> 2) + 4 * lh;
          if (key > qrow) st[g] = -3e38f;
        }
      }

      // p = exp2(s) (bounded, no max-shift), per-lane row-sum
#pragma unroll
      for (int g = 0; g < 16; ++g) {
        float e = exp2f(st[g]);
        st[g] = e;
        l_i += e;
      }

      // in-register P -> bf16 A-frags: 8 packs + 4 permlane32 swaps
      unsigned c8[8];
#pragma unroll
      for (int m = 0; m < 8; ++m) c8[m] = pack_bf2(st[2 * m], st[2 * m + 1]);
      asm("v_permlane32_swap_b32 %0, %1" : "+v"(c8[0]), "+v"(c8[2]));
      asm("v_permlane32_swap_b32 %0, %1" : "+v"(c8[1]), "+v"(c8[3]));
      asm("v_permlane32_swap_b32 %0, %1" : "+v"(c8[4]), "+v"(c8[6]));
      asm("v_permlane32_swap_b32 %0, %1" : "+v"(c8[5]), "+v"(c8[7]));
      union { unsigned u[4]; short8 s; } pa0, pa1;
      pa0.u[0] = c8[0]; pa0.u[1] = c8[1]; pa0.u[2] = c8[2]; pa0.u[3] = c8[3];
      pa1.u[0] = c8[4]; pa1.u[1] = c8[5]; pa1.u[2] = c8[6]; pa1.u[3] = c8[7];

      // O += P @ V   (D[qrow][dh], A = P rows, B = V^T rows)
#pragma unroll
      for (int dt = 0; dt < 4; ++dt) {
        int row = dt * 32 + l31;
        int p0 = ((kt * 2 + 0) * 2 + lh) ^ (row & 7);
        int p1 = ((kt * 2 + 1) * 2 + lh) ^ (row & 7);
        short8 vf0 = *(const short8*)&vtb[row * 64 + p0 * 8];
        short8 vf1 = *(const short8*)&vtb[row * 64 + p1 * 8];
        oacc[dt] = __builtin_amdgcn_mfma_f32_32x32x16_bf16(pa0.s, vf0, oacc[dt], 0, 0, 0);
        oacc[dt] = __builtin_amdgcn_mfma_f32_32x32x16_bf16(pa1.s, vf1, oacc[dt], 0, 0, 0);
      }
    }
  };

  const int kend = q0 + 64;            // last tile base; tile count qt*2+2 (even)
  stage(0, 0);                         // prologue: tile 0 -> buf0
  for (int k0 = 0; k0 < kend; k0 += 128) {
    // phase A: compute k0 from buf0; prefetch k0+64 -> buf1
    __syncthreads();                   // drains buf0's loads; all read buf1 done
    __builtin_amdgcn_sched_barrier(0);
    stage(k0 + 64, 8192);              // always valid: k0+64 <= kend
    compute(k0, Ks, Vt);
    // phase B: compute k0+64 from buf1; prefetch k0+128 -> buf0
    __syncthreads();                   // drains buf1's loads; all read buf0 done
    __builtin_amdgcn_sched_barrier(0);
    if (k0 + 128 <= kend) stage(k0 + 128, 0);
    compute(k0 + 64, Ks + 8192, Vt + 8192);
  }

  // epilogue: lane pair (l, l^32) holds complementary keys of the same qrow
  l_i += __shfl_xor(l_i, 32);
  float linv = 1.0f / l_i;
#pragma unroll
  for (int g = 0; g < 16; ++g) {
    int qrl = (g & 3) + 8 * (g >> 2) + 4 * lh;        // qrow index within wave
    float lg = __shfl(linv, qrl);                     // lane qrl holds that row's sum
    long rowoff = (long)(b * SEQ + q0 + w * 32 + qrl) * DIMSZ + h * HD + l31;
#pragma unroll
    for (int dt = 0; dt < 4; ++dt)
      yb[rowoff + dt * 32] = f2bf(oacc[dt][g] * lg);
  }
}

// ---------------------------------------------------------------------------
extern "C" void kernel_launch(void* const* d_in, const int* in_sizes, int n_in,
                              void* d_out, int out_size, void* d_ws, size_t ws_size,
                              hipStream_t stream) {
  const float* x  = (const float*)d_in[0];
  const float* Wq = (const float*)d_in[1];
  const float* Wk = (const float*)d_in[2];
  const float* Wv = (const float*)d_in[3];
  const float* Wo = (const float*)d_in[4];
  const float* qg = (const float*)d_in[5];
  float* out = (float*)d_out;

  const long MB = 1024 * 1024;
  char* ws = (char*)d_ws;
  u16* xb    = (u16*)(ws + 0 * MB);    // 16 MB (dead after QKV GEMM)
  u16* ybuf  = (u16*)(ws + 0 * MB);    // 16 MB (aliases xb; written by fattn)
  u16* Wqkvb = (u16*)(ws + 16 * MB);   // 12 MB
  u16* Wob   = (u16*)(ws + 28 * MB);   // 8 MB
  u16* qkv   = (u16*)(ws + 36 * MB);   // 24 MB
  u16* vtg   = (u16*)(ws + 60 * MB);   // 4 MB (V transposed)

  castAll<<<18432, 256, 0, stream>>>(x, Wq, Wk, Wv, Wo, xb, Wqkvb, Wob);

  // QKV GEMM: M=4096, N=3072; 256x192 tiles -> 16x16 = 256 blocks (full fill)
  gemmX<3, false><<<256, 512, 0, stream>>>(xb, Wqkvb, qkv, NTOK, QKVD, DIMSZ);

  const float qsc = 0.08838834764831845f * 1.44269504088896f;  // scale*log2e
  prep<<<20736, 256, 0, stream>>>(qkv, qg, qsc, vtg);

  // 16 q-tiles (128 rows) x 32 (h,b) = 512 blocks of 256 threads,
  // ordered so (bid, bid+256) pair to a uniform 34 kv-iters per CU.
  fattn<<<512, 256, 0, stream>>>(qkv, qkv + 2048, vtg, ybuf);

  // Output GEMM: M=4096, N=2048; 256x128 tiles -> 16x16 = 256 blocks
  gemmX<2, true><<<256, 512, 0, stream>>>(ybuf, Wob, out, NTOK, DIMSZ, DIMSZ);
}